// Round 4
// baseline (430.932 us; speedup 1.0000x reference)
//
#include <hip/hip_runtime.h>
#include <cstdint>
#include <cstddef>

typedef unsigned short u16;
typedef unsigned int u32;
typedef __bf16 bf16x8 __attribute__((ext_vector_type(8)));
typedef float floatx4 __attribute__((ext_vector_type(4)));
typedef float floatx16 __attribute__((ext_vector_type(16)));

#define B_ 2
#define S_ 2048
#define D_ 1024
#define H_ 16
#define DFF_ 4096
#define BS_ 4096   // B_*S_

__device__ __forceinline__ u16 f2bf(float f) {
  u32 u = __builtin_bit_cast(u32, f);
  u += 0x7fffu + ((u >> 16) & 1u);
  return (u16)(u >> 16);
}
__device__ __forceinline__ float bf2f(u16 h) {
  u32 u = ((u32)h) << 16;
  return __builtin_bit_cast(float, u);
}

// async global->LDS, 16B per lane (attention staging only)
__device__ __forceinline__ void gl_lds16(const u16* g, u16* l) {
  __builtin_amdgcn_global_load_lds(
      (const __attribute__((address_space(1))) void*)g,
      (__attribute__((address_space(3))) void*)l, 16, 0, 0);
}

// ===========================================================================
// Fragment-linear layout (for 32x32x16 bf16 MFMA operands), verified by the
// R3 kernel's LDS mapping: for operand X[dim32][K]:
//   addr(e, k) = ((e>>5)*(K/16) + (k>>4))*512 + ((e&31) + 32*((k>>3)&1))*8 + (k&7)
// A wave's fragment for (block eb, chunk kc) is 64 lanes x 16B, contiguous.
// ===========================================================================

// ---------------------------------------------------------------------------
// All weight transposes (+bf16 cast) into fragment-linear layout, ONE kernel.
// mode 0: nb = col>>5.  mode 1/2 (gate/up): nb = (col>>5)*2 (+1 for up) so the
// gemm wave's ni=0/1 fragments are the matching gate/up column blocks.
// ---------------------------------------------------------------------------
__global__ void prep_weights(const float* __restrict__ wq, const float* __restrict__ wk,
                             const float* __restrict__ wv, const float* __restrict__ wo,
                             const float* __restrict__ wg, const float* __restrict__ wu,
                             const float* __restrict__ wd,
                             u16* __restrict__ wqkv_t, u16* __restrict__ wo_t,
                             u16* __restrict__ wgu_t, u16* __restrict__ wdn_t) {
  __shared__ float tile[32][33];
  const int id = blockIdx.x;
  const float* src;
  u16* dst;
  int R, C, bx, by, mode, KC;
  if (id < 3072) {
    const int which = id >> 10, lo = id & 1023;
    src = which == 0 ? wq : (which == 1 ? wk : wv);
    dst = wqkv_t + which * 1024 * 1024;
    R = 1024; C = 1024; bx = lo & 31; by = lo >> 5; mode = 0; KC = 64;
  } else if (id < 4096) {
    const int lo = id - 3072;
    src = wo; dst = wo_t; R = 1024; C = 1024; bx = lo & 31; by = lo >> 5; mode = 0; KC = 64;
  } else if (id < 8192) {
    const int lo = id - 4096;
    src = wg; dst = wgu_t; R = 1024; C = 4096; bx = lo & 127; by = lo >> 7; mode = 1; KC = 64;
  } else if (id < 12288) {
    const int lo = id - 8192;
    src = wu; dst = wgu_t; R = 1024; C = 4096; bx = lo & 127; by = lo >> 7; mode = 2; KC = 64;
  } else {
    const int lo = id - 12288;
    src = wd; dst = wdn_t; R = 4096; C = 1024; bx = lo & 31; by = lo >> 5; mode = 0; KC = 256;
  }
  const int tx = threadIdx.x, ty = threadIdx.y;
  const int c0 = bx * 32, r0 = by * 32;
#pragma unroll
  for (int i = 0; i < 4; i++)
    tile[ty + i * 8][tx] = src[(size_t)(r0 + ty + i * 8) * C + c0 + tx];
  __syncthreads();
  // element (k = r0+tx, n = c0+ty+i*8), value tile[tx][ty+i*8]
#pragma unroll
  for (int i = 0; i < 4; i++) {
    const int oc = c0 + ty + i * 8;
    const int nb = (mode == 0) ? (oc >> 5) : ((oc >> 5) * 2 + (mode == 2 ? 1 : 0));
    const int kc = (r0 >> 4) + (tx >> 4);
    const size_t addr = ((size_t)nb * KC + kc) * 512 +
                        ((oc & 31) + 32 * ((tx >> 3) & 1)) * 8 + (tx & 7);
    dst[addr] = f2bf(tile[tx][ty + i * 8]);
  }
}

// ---------------------------------------------------------------------------
// RMSNorm: x [rows][1024] f32, g [1024] f32 -> out bf16 fragment-linear (KC=64)
// ---------------------------------------------------------------------------
__global__ __launch_bounds__(256) void rmsnorm_kernel(const float* __restrict__ x,
                                                      const float* __restrict__ g,
                                                      u16* __restrict__ out) {
  const int row = blockIdx.x, t = threadIdx.x;
  const float4 v = ((const float4*)(x + (size_t)row * 1024))[t];
  float ss = v.x * v.x + v.y * v.y + v.z * v.z + v.w * v.w;
#pragma unroll
  for (int off = 32; off > 0; off >>= 1) ss += __shfl_xor(ss, off);
  __shared__ float red[4];
  if ((t & 63) == 0) red[t >> 6] = ss;
  __syncthreads();
  ss = red[0] + red[1] + red[2] + red[3];
  const float inv = rsqrtf(ss * (1.0f / 1024.0f) + 1e-6f);
  const float4 gv = ((const float4*)g)[t];
  uint2 o;
  o.x = (u32)f2bf(v.x * inv * gv.x) | ((u32)f2bf(v.y * inv * gv.y) << 16);
  o.y = (u32)f2bf(v.z * inv * gv.z) | ((u32)f2bf(v.w * inv * gv.w) << 16);
  // k = 4t..4t+3 -> kc=t>>2, khalf=(t>>1)&1, j=(t&1)*4
  u16* dst = out + ((size_t)(row >> 5) * 64 + (t >> 2)) * 512 +
             ((row & 31) + 32 * ((t >> 1) & 1)) * 8 + (t & 1) * 4;
  *(uint2*)dst = o;
}

// ---------------------------------------------------------------------------
// V^T: qkv v-block [b,s,h,dv] -> vT [b][h][dv=64][S].  64x64 LDS tile.
// ---------------------------------------------------------------------------
__global__ __launch_bounds__(256) void vtrans_kernel(const u16* __restrict__ qkv,
                                                     u16* __restrict__ vT) {
  __shared__ u16 tile[64][72];
  const int t = threadIdx.x;
  const int s0 = blockIdx.x * 64, h = blockIdx.y, b = blockIdx.z;
  const int r = t >> 2, cc = t & 3;
  const u16* src = qkv + (size_t)(b * S_ + s0 + r) * 3072 + 2 * D_ + h * 64 + cc * 16;
  *(uint4*)(&tile[r][cc * 16]) = *(const uint4*)src;
  *(uint4*)(&tile[r][cc * 16 + 8]) = *(const uint4*)(src + 8);
  __syncthreads();
  union { uint4 u[2]; u16 s[16]; } o;
#pragma unroll
  for (int j = 0; j < 16; j++) o.s[j] = tile[cc * 16 + j][r];
  u16* dst = vT + (size_t)((b * H_ + h) * 64 + r) * S_ + s0 + cc * 16;
  *(uint4*)dst = o.u[0];
  *(uint4*)(dst + 8) = o.u[1];
}

// ---------------------------------------------------------------------------
// Register-fragment bf16 GEMM (no LDS, no memory-draining barriers):
// C[M,N] = A[M,K] @ Bt[N,K]^T with BOTH operands in fragment-linear layout.
// Block 128 x BN, 4 waves (2x2), wave tile 64 x (BN/2); 32x32x16 MFMA.
// K-loop: register ping-pong, 4 k-chunks (64 k) per stage, loads for stage
// i+1 issued before MFMAs of stage i (AITER-style 1:1 interleave, fine vmcnt).
// Raw s_barrier keeps wave pairs in lockstep so L1 catches 2x operand reuse.
// EPI 0: bf16 row-major. EPI 1: f32 row-major + f32 residual.
// EPI 2: silu(gate)*up -> bf16 fragment-linear hid (KC=256) for down GEMM.
// ---------------------------------------------------------------------------
template <int BN, int EPI>
__global__ __launch_bounds__(256) void gemm_rf(const u16* __restrict__ Af,
                                               const u16* __restrict__ Bf,
                                               void* __restrict__ Cout,
                                               const float* __restrict__ res,
                                               int M, int N, int K) {
  constexpr int NTI = BN / 64;
  const int t = threadIdx.x, w = t >> 6, l = t & 63;
  const int wm = w >> 1, wn = w & 1;
  const int m0 = blockIdx.y * 128, n0 = blockIdx.x * BN;
  const int c31 = l & 31, khalf = l >> 5;
  const int KC = K >> 4;

  const u16* aP[2];
  const u16* bP[NTI];
#pragma unroll
  for (int mi = 0; mi < 2; mi++)
    aP[mi] = Af + ((size_t)((m0 >> 5) + wm * 2 + mi) * KC) * 512 + l * 8;
#pragma unroll
  for (int ni = 0; ni < NTI; ni++)
    bP[ni] = Bf + ((size_t)((n0 >> 5) + wn * NTI + ni) * KC) * 512 + l * 8;

  floatx16 acc[2][NTI] = {};
  bf16x8 a0[2][4], b0[NTI][4], a1[2][4], b1[NTI][4];

#define LD(ab, bb)                                                         \
  {                                                                        \
    _Pragma("unroll") for (int mi = 0; mi < 2; mi++)                       \
        _Pragma("unroll") for (int u = 0; u < 4; u++)                      \
            ab[mi][u] = *(const bf16x8*)(aP[mi] + u * 512);                \
    _Pragma("unroll") for (int ni = 0; ni < NTI; ni++)                     \
        _Pragma("unroll") for (int u = 0; u < 4; u++)                      \
            bb[ni][u] = *(const bf16x8*)(bP[ni] + u * 512);                \
    _Pragma("unroll") for (int mi = 0; mi < 2; mi++) aP[mi] += 2048;       \
    _Pragma("unroll") for (int ni = 0; ni < NTI; ni++) bP[ni] += 2048;     \
  }
#define FM(ab, bb)                                                         \
  {                                                                        \
    _Pragma("unroll") for (int u = 0; u < 4; u++)                          \
        _Pragma("unroll") for (int mi = 0; mi < 2; mi++)                   \
            _Pragma("unroll") for (int ni = 0; ni < NTI; ni++)             \
                acc[mi][ni] = __builtin_amdgcn_mfma_f32_32x32x16_bf16(     \
                    ab[mi][u], bb[ni][u], acc[mi][ni], 0, 0, 0);           \
  }

  LD(a0, b0);
  const int NIT = K / 64;
  for (int it = 0; it < NIT - 2; it += 2) {
    LD(a1, b1);
    FM(a0, b0);
    __builtin_amdgcn_s_barrier();
    LD(a0, b0);
    FM(a1, b1);
  }
  LD(a1, b1);
  FM(a0, b0);
  FM(a1, b1);
#undef LD
#undef FM

  if (EPI == 2) {
    // wave wn owns gate block (nb even, ni=0) and up block (nb odd, ni=1),
    // both mapping to output cols (bx*2+wn)*32 + c31 of hid (frag-linear, KC=256)
    const int colb = (int)blockIdx.x * 2 + wn;
#pragma unroll
    for (int mi = 0; mi < 2; mi++) {
      u16* outp = (u16*)Cout +
                  (((size_t)((m0 >> 5) + wm * 2 + mi) * 256 + colb * 2 + (c31 >> 4)) * 512 +
                   32 * ((c31 >> 3) & 1) * 8 + (c31 & 7));
#pragma unroll
      for (int reg = 0; reg < 16; reg++) {
        const int mir = (reg & 3) + 8 * (reg >> 2) + 4 * khalf;  // row&31
        const float g = acc[mi][0][reg];
        const float u = acc[mi][1][reg];
        outp[(size_t)mir * 8] = f2bf(g / (1.f + __expf(-g)) * u);
      }
    }
  } else {
#pragma unroll
    for (int mi = 0; mi < 2; mi++)
#pragma unroll
      for (int ni = 0; ni < NTI; ni++) {
        const int col = n0 + (wn * NTI + ni) * 32 + c31;
#pragma unroll
        for (int reg = 0; reg < 16; reg++) {
          const int row = m0 + wm * 64 + mi * 32 + (reg & 3) + 8 * (reg >> 2) + 4 * khalf;
          const size_t idx = (size_t)row * N + col;
          if (EPI == 0) ((u16*)Cout)[idx] = f2bf(acc[mi][ni][reg]);
          else          ((float*)Cout)[idx] = acc[mi][ni][reg] + res[idx];
        }
      }
  }
}

// ---------------------------------------------------------------------------
// Causal attention (strict k<q), softmax = exp(s)/(sum+1e-9), flash-style.
// q-tile 128 (wave owns 32 q rows), k-tile 64, double-buffered LDS staging via
// global_load_lds; one barrier per iter; P per-wave in XOR-swizzled LDS.
// Epilogue writes av in fragment-linear layout (KC=64) for the wo GEMM.
// ---------------------------------------------------------------------------
__global__ __launch_bounds__(256) void attn_kernel(const u16* __restrict__ qkv,
                                                   const u16* __restrict__ vT,
                                                   u16* __restrict__ av) {
  __shared__ u16 SM[2 * 8192];       // [buf][ K:2x64x32 | V:2x64x32 ]
  __shared__ u16 Ps[4 * 2048];       // per-wave P [32 q][64 k], 16B-chunk swizzle
  const int t = threadIdx.x, w = t >> 6, l = t & 63;
  const int lrow = l & 15, lk = l >> 4;
  const int bh = blockIdx.x;         // b*16 + h
  const int b = bh >> 4, h = bh & 15;
  const int qt = 15 - (int)blockIdx.y;   // heavy tiles dispatch first
  const int qbase = qt * 128 + w * 32;
  const int ktmax = 2 * qt + 1;
  u16* Pw = Ps + w * 2048;

  bf16x8 aq[2][2];
#pragma unroll
  for (int sub = 0; sub < 2; sub++)
#pragma unroll
    for (int half = 0; half < 2; half++)
      aq[sub][half] = *(const bf16x8*)(qkv + (size_t)(b * S_ + qbase + sub * 16 + lrow) * 3072 +
                                       h * 64 + half * 32 + lk * 8);

  const u16* gcur[4];
  int gstep[4], loff[4];
#pragma unroll
  for (int i = 0; i < 4; i++) {
    const int c = w + 4 * i;
    const int half = (c >> 2) & 1, grp = c & 3;
    if (c < 8) {
      gcur[i] = qkv + (size_t)(b * S_ + grp * 16 + (l >> 2)) * 3072 + D_ + h * 64 +
                half * 32 + (l & 3) * 8;
      gstep[i] = 64 * 3072;
      loff[i] = half * 2048 + grp * 512;
    } else {
      gcur[i] = vT + (size_t)(bh * 64 + grp * 16 + (l >> 2)) * S_ + half * 32 + (l & 3) * 8;
      gstep[i] = 64;
      loff[i] = 4096 + half * 2048 + grp * 512;
    }
  }

  floatx4 oacc[2][4] = {};
  float den[2][4] = {};

  int cur = 0;
#pragma unroll
  for (int i = 0; i < 4; i++) { gl_lds16(gcur[i], SM + loff[i]); gcur[i] += gstep[i]; }

  for (int kt = 0; kt <= ktmax; kt++) {
    __syncthreads();
    if (kt < ktmax) {
#pragma unroll
      for (int i = 0; i < 4; i++) {
        gl_lds16(gcur[i], SM + (cur ^ 1) * 8192 + loff[i]);
        gcur[i] += gstep[i];
      }
    }
    const u16* Kbuf = SM + cur * 8192;
    const u16* Vbuf = Kbuf + 4096;

    bf16x8 bk[4][2];
#pragma unroll
    for (int ct = 0; ct < 4; ct++)
#pragma unroll
      for (int half = 0; half < 2; half++)
        bk[ct][half] = *(const bf16x8*)(Kbuf + half * 2048 + (ct * 16 + lrow) * 32 + lk * 8);
    floatx4 sf[2][4] = {};
#pragma unroll
    for (int sub = 0; sub < 2; sub++)
#pragma unroll
      for (int ct = 0; ct < 4; ct++) {
        sf[sub][ct] = __builtin_amdgcn_mfma_f32_16x16x32_bf16(aq[sub][0], bk[ct][0],
                                                              sf[sub][ct], 0, 0, 0);
        sf[sub][ct] = __builtin_amdgcn_mfma_f32_16x16x32_bf16(aq[sub][1], bk[ct][1],
                                                              sf[sub][ct], 0, 0, 0);
      }

#pragma unroll
    for (int sub = 0; sub < 2; sub++)
#pragma unroll
      for (int ct = 0; ct < 4; ct++) {
        const int kpos = kt * 64 + ct * 16 + lrow;
#pragma unroll
        for (int r = 0; r < 4; r++) {
          const int qpos = qbase + sub * 16 + lk * 4 + r;
          const float p = (kpos < qpos) ? __expf(sf[sub][ct][r] * 0.125f) : 0.f;
          den[sub][r] += p;
          const int prow = sub * 16 + lk * 4 + r;
          const int pcol = ct * 16 + lrow;
          Pw[prow * 64 + ((((pcol >> 3) ^ (prow & 7))) << 3) + (pcol & 7)] = f2bf(p);
        }
      }

    bf16x8 ap[2][2], bv[4][2];
#pragma unroll
    for (int sub = 0; sub < 2; sub++)
#pragma unroll
      for (int kh = 0; kh < 2; kh++) {
        const int prow = sub * 16 + lrow;
        ap[sub][kh] = *(const bf16x8*)(Pw + prow * 64 + (((kh * 4 + lk) ^ (prow & 7)) << 3));
      }
#pragma unroll
    for (int ni = 0; ni < 4; ni++)
#pragma unroll
      for (int kh = 0; kh < 2; kh++)
        bv[ni][kh] = *(const bf16x8*)(Vbuf + kh * 2048 + (ni * 16 + lrow) * 32 + lk * 8);
#pragma unroll
    for (int sub = 0; sub < 2; sub++)
#pragma unroll
      for (int ni = 0; ni < 4; ni++) {
        oacc[sub][ni] = __builtin_amdgcn_mfma_f32_16x16x32_bf16(ap[sub][0], bv[ni][0],
                                                                oacc[sub][ni], 0, 0, 0);
        oacc[sub][ni] = __builtin_amdgcn_mfma_f32_16x16x32_bf16(ap[sub][1], bv[ni][1],
                                                                oacc[sub][ni], 0, 0, 0);
      }
    cur ^= 1;
  }

#pragma unroll
  for (int sub = 0; sub < 2; sub++)
#pragma unroll
    for (int r = 0; r < 4; r++) {
      float d = den[sub][r];
      d += __shfl_xor(d, 1);
      d += __shfl_xor(d, 2);
      d += __shfl_xor(d, 4);
      d += __shfl_xor(d, 8);
      den[sub][r] = d;
    }
  // av fragment-linear: row = b*S_ + qbase + rowl, col = h*64 + ni*16 + lrow
  // mb = b*64 + qt*4 + w; kc = h*4 + ni; slot = rowl + 32*(lrow>>3); j = lrow&7
#pragma unroll
  for (int sub = 0; sub < 2; sub++)
#pragma unroll
    for (int ni = 0; ni < 4; ni++)
#pragma unroll
      for (int r = 0; r < 4; r++) {
        const int rowl = sub * 16 + lk * 4 + r;
        const size_t addr = ((size_t)(b * 64 + qt * 4 + w) * 64 + h * 4 + ni) * 512 +
                            (rowl + 32 * (lrow >> 3)) * 8 + (lrow & 7);
        av[addr] = f2bf(oacc[sub][ni][r] / (den[sub][r] + 1e-9f));
      }
}

// ---------------------------------------------------------------------------
// Workspace layout (bytes)
// ---------------------------------------------------------------------------
#define OFF_WQKV 0u            // [96 nb][64 kc][512] bf16
#define OFF_WO   6291456u      // [32][64][512] bf16
#define OFF_WGU  8388608u      // [256][64][512] bf16 (gate/up nb-interleaved)
#define OFF_WDN  25165824u     // [32][256][512] bf16
#define OFF_H1   33554432u     // frag [128][64][512] bf16
#define OFF_QKV  41943040u     // row-major [4096][3072] bf16
#define OFF_VT   67108864u     // [2][16][64][2048] bf16
#define OFF_AV   75497472u     // frag [128][64][512] bf16
#define OFF_X1   83886080u     // row-major [4096][1024] f32
#define OFF_H2   100663296u    // frag [128][64][512] bf16
#define OFF_HID  109051904u    // frag [128][256][512] bf16

extern "C" void kernel_launch(void* const* d_in, const int* in_sizes, int n_in,
                              void* d_out, int out_size, void* d_ws, size_t ws_size,
                              hipStream_t stream) {
  const float* x      = (const float*)d_in[0];
  const float* w_q    = (const float*)d_in[1];
  const float* w_k    = (const float*)d_in[2];
  const float* w_v    = (const float*)d_in[3];
  const float* w_o    = (const float*)d_in[4];
  const float* w_gate = (const float*)d_in[5];
  const float* w_up   = (const float*)d_in[6];
  const float* w_down = (const float*)d_in[7];
  const float* g1     = (const float*)d_in[8];
  const float* g2     = (const float*)d_in[9];

  char* ws = (char*)d_ws;
  u16* wqkv_t = (u16*)(ws + OFF_WQKV);
  u16* wo_t   = (u16*)(ws + OFF_WO);
  u16* wgu_t  = (u16*)(ws + OFF_WGU);
  u16* wdn_t  = (u16*)(ws + OFF_WDN);
  u16* h1     = (u16*)(ws + OFF_H1);
  u16* qkv    = (u16*)(ws + OFF_QKV);
  u16* vT     = (u16*)(ws + OFF_VT);
  u16* av     = (u16*)(ws + OFF_AV);
  float* x1   = (float*)(ws + OFF_X1);
  u16* h2     = (u16*)(ws + OFF_H2);
  u16* hid    = (u16*)(ws + OFF_HID);
  float* out  = (float*)d_out;

  prep_weights<<<16384, dim3(32, 8), 0, stream>>>(w_q, w_k, w_v, w_o, w_gate, w_up, w_down,
                                                  wqkv_t, wo_t, wgu_t, wdn_t);

  rmsnorm_kernel<<<BS_, 256, 0, stream>>>(x, g1, h1);
  gemm_rf<128, 0><<<dim3(3072 / 128, BS_ / 128), 256, 0, stream>>>(h1, wqkv_t, qkv, nullptr,
                                                                   BS_, 3072, 1024);
  vtrans_kernel<<<dim3(S_ / 64, H_, B_), 256, 0, stream>>>(qkv, vT);
  attn_kernel<<<dim3(32, 16), 256, 0, stream>>>(qkv, vT, av);
  gemm_rf<64, 1><<<dim3(1024 / 64, BS_ / 128), 256, 0, stream>>>(av, wo_t, x1, x,
                                                                 BS_, 1024, 1024);
  rmsnorm_kernel<<<BS_, 256, 0, stream>>>(x1, g2, h2);
  gemm_rf<128, 2><<<dim3(8192 / 128, BS_ / 128), 256, 0, stream>>>(h2, wgu_t, hid, nullptr,
                                                                   BS_, 8192, 1024);
  gemm_rf<64, 1><<<dim3(1024 / 64, BS_ / 128), 256, 0, stream>>>(hid, wdn_t, out, x1,
                                                                 BS_, 1024, 4096);
}

// Round 5
// 397.534 us; speedup vs baseline: 1.0840x; 1.0840x over previous
//
#include <hip/hip_runtime.h>
#include <cstdint>
#include <cstddef>

typedef unsigned short u16;
typedef unsigned int u32;
typedef __bf16 bf16x8 __attribute__((ext_vector_type(8)));
typedef float floatx4 __attribute__((ext_vector_type(4)));
typedef float floatx16 __attribute__((ext_vector_type(16)));

#define B_ 2
#define S_ 2048
#define D_ 1024
#define H_ 16
#define DFF_ 4096
#define BS_ 4096   // B_*S_

__device__ __forceinline__ u16 f2bf(float f) {
  u32 u = __builtin_bit_cast(u32, f);
  u += 0x7fffu + ((u >> 16) & 1u);
  return (u16)(u >> 16);
}
__device__ __forceinline__ float bf2f(u16 h) {
  u32 u = ((u32)h) << 16;
  return __builtin_bit_cast(float, u);
}

// async global->LDS, 16B per lane; LDS dest is wave-uniform base + lane*16
__device__ __forceinline__ void gl_lds16(const u16* g, u16* l) {
  __builtin_amdgcn_global_load_lds(
      (const __attribute__((address_space(1))) void*)g,
      (__attribute__((address_space(3))) void*)l, 16, 0, 0);
}

// ---------------------------------------------------------------------------
// All weight transposes (+bf16 cast) in ONE kernel.  32x32 LDS tiles.
// mode 0: out row = col. mode 1/2 (gate/up): 32-col interleave ->
//   row' = (c>>5)*64 + (c&31) (+32 for up), so gemm waves see gate|up pairs.
// ---------------------------------------------------------------------------
__global__ void prep_weights(const float* __restrict__ wq, const float* __restrict__ wk,
                             const float* __restrict__ wv, const float* __restrict__ wo,
                             const float* __restrict__ wg, const float* __restrict__ wu,
                             const float* __restrict__ wd,
                             u16* __restrict__ wqkv_t, u16* __restrict__ wo_t,
                             u16* __restrict__ wgu_t, u16* __restrict__ wdn_t) {
  __shared__ float tile[32][33];
  const int id = blockIdx.x;
  const float* src;
  u16* dst;
  int R, C, bx, by, mode;
  if (id < 3072) {
    const int which = id >> 10, lo = id & 1023;
    src = which == 0 ? wq : (which == 1 ? wk : wv);
    dst = wqkv_t + which * 1024 * 1024;
    R = 1024; C = 1024; bx = lo & 31; by = lo >> 5; mode = 0;
  } else if (id < 4096) {
    const int lo = id - 3072;
    src = wo; dst = wo_t; R = 1024; C = 1024; bx = lo & 31; by = lo >> 5; mode = 0;
  } else if (id < 8192) {
    const int lo = id - 4096;
    src = wg; dst = wgu_t; R = 1024; C = 4096; bx = lo & 127; by = lo >> 7; mode = 1;
  } else if (id < 12288) {
    const int lo = id - 8192;
    src = wu; dst = wgu_t; R = 1024; C = 4096; bx = lo & 127; by = lo >> 7; mode = 2;
  } else {
    const int lo = id - 12288;
    src = wd; dst = wdn_t; R = 4096; C = 1024; bx = lo & 31; by = lo >> 5; mode = 0;
  }
  const int tx = threadIdx.x, ty = threadIdx.y;
  const int c0 = bx * 32, r0 = by * 32;
#pragma unroll
  for (int i = 0; i < 4; i++)
    tile[ty + i * 8][tx] = src[(size_t)(r0 + ty + i * 8) * C + c0 + tx];
  __syncthreads();
#pragma unroll
  for (int i = 0; i < 4; i++) {
    const int oc = c0 + ty + i * 8;
    const int orow = (mode == 0) ? oc
                                 : ((oc >> 5) * 64 + (oc & 31) + (mode == 2 ? 32 : 0));
    dst[(size_t)orow * R + r0 + tx] = f2bf(tile[tx][ty + i * 8]);
  }
}

// ---------------------------------------------------------------------------
// RMSNorm: x [rows][1024] f32, g [1024] f32 -> out bf16 [rows][1024]
// ---------------------------------------------------------------------------
__global__ __launch_bounds__(256) void rmsnorm_kernel(const float* __restrict__ x,
                                                      const float* __restrict__ g,
                                                      u16* __restrict__ out) {
  const int row = blockIdx.x, t = threadIdx.x;
  const float4 v = ((const float4*)(x + (size_t)row * 1024))[t];
  float ss = v.x * v.x + v.y * v.y + v.z * v.z + v.w * v.w;
#pragma unroll
  for (int off = 32; off > 0; off >>= 1) ss += __shfl_xor(ss, off);
  __shared__ float red[4];
  if ((t & 63) == 0) red[t >> 6] = ss;
  __syncthreads();
  ss = red[0] + red[1] + red[2] + red[3];
  const float inv = rsqrtf(ss * (1.0f / 1024.0f) + 1e-6f);
  const float4 gv = ((const float4*)g)[t];
  uint2 o;
  o.x = (u32)f2bf(v.x * inv * gv.x) | ((u32)f2bf(v.y * inv * gv.y) << 16);
  o.y = (u32)f2bf(v.z * inv * gv.z) | ((u32)f2bf(v.w * inv * gv.w) << 16);
  ((uint2*)(out + (size_t)row * 1024))[t] = o;
}

// ---------------------------------------------------------------------------
// V^T: qkv v-block [b,s,h,dv] -> vT [b][h][dv=64][S].  64x64 LDS tile.
// ---------------------------------------------------------------------------
__global__ __launch_bounds__(256) void vtrans_kernel(const u16* __restrict__ qkv,
                                                     u16* __restrict__ vT) {
  __shared__ u16 tile[64][72];
  const int t = threadIdx.x;
  const int s0 = blockIdx.x * 64, h = blockIdx.y, b = blockIdx.z;
  const int r = t >> 2, cc = t & 3;
  const u16* src = qkv + (size_t)(b * S_ + s0 + r) * 3072 + 2 * D_ + h * 64 + cc * 16;
  *(uint4*)(&tile[r][cc * 16]) = *(const uint4*)src;
  *(uint4*)(&tile[r][cc * 16 + 8]) = *(const uint4*)(src + 8);
  __syncthreads();
  union { uint4 u[2]; u16 s[16]; } o;
#pragma unroll
  for (int j = 0; j < 16; j++) o.s[j] = tile[cc * 16 + j][r];
  u16* dst = vT + (size_t)((b * H_ + h) * 64 + r) * S_ + s0 + cc * 16;
  *(uint4*)dst = o.u[0];
  *(uint4*)(dst + 8) = o.u[1];
}

// ---------------------------------------------------------------------------
// bf16 GEMM (R3-verified): C[M,N] = A[M,K] @ Bt[N,K]^T.
// 32x32x16 MFMA, BK=64, 128xBN tile, 4 waves (2x2), wave tile 64x(BN/2).
// EPI 0: bf16 out. EPI 1: f32 out + f32 residual.
// ---------------------------------------------------------------------------
template <int BN, int EPI>
__global__ __launch_bounds__(256) void gemm_bt(const u16* __restrict__ A,
                                               const u16* __restrict__ Bt,
                                               void* __restrict__ Cout,
                                               const float* __restrict__ res,
                                               int M, int N, int K) {
  __shared__ u16 As[128 * 64];
  __shared__ u16 Bs[BN * 64];
  constexpr int NTI = BN / 64;        // n-subtiles of 32 per wave
  constexpr int NSEG = 16 + BN / 8;   // 1024B staging segments
  constexpr int SPW = NSEG / 4;
  const int t = threadIdx.x, w = t >> 6, l = t & 63;
  const int m0 = blockIdx.y * 128, n0 = blockIdx.x * BN;
  const int wm = w >> 1, wn = w & 1;
  const int c31 = l & 31, khalf = l >> 5;

  const u16* gsrc[SPW];
  u16* ldst[SPW];
  {
    const int rl = l >> 3, ch = (l & 7) ^ rl;
#pragma unroll
    for (int i = 0; i < SPW; i++) {
      const int s = w * SPW + i;
      if (s < 16) {
        gsrc[i] = A + (size_t)(m0 + s * 8 + rl) * K + ch * 8;
        ldst[i] = As + s * 512;
      } else {
        gsrc[i] = Bt + (size_t)(n0 + (s - 16) * 8 + rl) * K + ch * 8;
        ldst[i] = Bs + (s - 16) * 512;
      }
    }
  }

  floatx16 acc[2][NTI] = {};

  for (int kk = 0; kk < K; kk += 64) {
    __syncthreads();
#pragma unroll
    for (int i = 0; i < SPW; i++) gl_lds16(gsrc[i], ldst[i]);
#pragma unroll
    for (int i = 0; i < SPW; i++) gsrc[i] += 64;
    __syncthreads();

#pragma unroll
    for (int ks = 0; ks < 4; ks++) {
      bf16x8 af[2], bfr[NTI];
#pragma unroll
      for (int mi = 0; mi < 2; mi++) {
        const int row = wm * 64 + mi * 32 + c31;
        const int e = (ks * 2 + khalf) ^ (row & 7);
        af[mi] = *(const bf16x8*)(As + row * 64 + e * 8);
      }
#pragma unroll
      for (int ni = 0; ni < NTI; ni++) {
        const int row = wn * (BN / 2) + ni * 32 + c31;
        const int e = (ks * 2 + khalf) ^ (row & 7);
        bfr[ni] = *(const bf16x8*)(Bs + row * 64 + e * 8);
      }
#pragma unroll
      for (int mi = 0; mi < 2; mi++)
#pragma unroll
        for (int ni = 0; ni < NTI; ni++)
          acc[mi][ni] = __builtin_amdgcn_mfma_f32_32x32x16_bf16(af[mi], bfr[ni],
                                                                acc[mi][ni], 0, 0, 0);
    }
  }

  // C/D layout (32x32): col = lane&31, row = (reg&3) + 8*(reg>>2) + 4*(lane>>5)
#pragma unroll
  for (int mi = 0; mi < 2; mi++)
#pragma unroll
    for (int ni = 0; ni < NTI; ni++) {
      const int col = n0 + wn * (BN / 2) + ni * 32 + c31;
#pragma unroll
      for (int reg = 0; reg < 16; reg++) {
        const int row = m0 + wm * 64 + mi * 32 + (reg & 3) + 8 * (reg >> 2) + 4 * khalf;
        const size_t idx = (size_t)row * N + col;
        if (EPI == 0) ((u16*)Cout)[idx] = f2bf(acc[mi][ni][reg]);
        else          ((float*)Cout)[idx] = acc[mi][ni][reg] + res[idx];
      }
    }
}

// ---------------------------------------------------------------------------
// Big-tile GEMM: 256x128 block, 4 waves (2x2), wave tile 128x64.
// Ratio: 256 MFMA (~1082 cyc) vs ~96KB LDS reads + 48KB writes (~1500 cyc)
// -> LDS ceiling 72% (vs 48% for the 128x128 tile).
// EPI 0: bf16 row-major out. EPI 2: silu(gate)*up -> bf16 [M][4096]
// (B rows are gate/up 32-col interleaved: ni=0 gate, ni=1 up).
// ---------------------------------------------------------------------------
template <int EPI>
__global__ __launch_bounds__(256, 2) void gemm_big(const u16* __restrict__ A,
                                                   const u16* __restrict__ Bt,
                                                   void* __restrict__ Cout,
                                                   int M, int N, int K) {
  __shared__ u16 As[256 * 64];
  __shared__ u16 Bs[128 * 64];
  const int t = threadIdx.x, w = t >> 6, l = t & 63;
  const int m0 = blockIdx.y * 256, n0 = blockIdx.x * 128;
  const int wm = w >> 1, wn = w & 1;
  const int c31 = l & 31, khalf = l >> 5;

  // staging: 48 x 1KB segments (A: 32, B: 16); wave-uniform base + lane offset
  const int rl = l >> 3, ch = (l & 7) ^ rl;
  const int voff = rl * K + ch * 8;         // per-lane (divergent) part
  const u16* baseA = A + (size_t)m0 * K;
  const u16* baseB = Bt + (size_t)n0 * K;

  floatx16 acc[4][2] = {};

  for (int kk = 0; kk < K; kk += 64) {
    __syncthreads();
#pragma unroll
    for (int i = 0; i < 12; i++) {
      const int s = w * 12 + i;             // wave-uniform
      if (s < 32)
        gl_lds16(baseA + (size_t)s * 8 * K + voff + kk, As + s * 512);
      else
        gl_lds16(baseB + (size_t)(s - 32) * 8 * K + voff + kk, Bs + (s - 32) * 512);
    }
    __syncthreads();

#pragma unroll
    for (int ks = 0; ks < 4; ks++) {
      bf16x8 af[4], bfr[2];
#pragma unroll
      for (int mi = 0; mi < 4; mi++) {
        const int row = wm * 128 + mi * 32 + c31;
        const int e = (ks * 2 + khalf) ^ (row & 7);
        af[mi] = *(const bf16x8*)(As + row * 64 + e * 8);
      }
#pragma unroll
      for (int ni = 0; ni < 2; ni++) {
        const int row = wn * 64 + ni * 32 + c31;
        const int e = (ks * 2 + khalf) ^ (row & 7);
        bfr[ni] = *(const bf16x8*)(Bs + row * 64 + e * 8);
      }
#pragma unroll
      for (int mi = 0; mi < 4; mi++)
#pragma unroll
        for (int ni = 0; ni < 2; ni++)
          acc[mi][ni] = __builtin_amdgcn_mfma_f32_32x32x16_bf16(af[mi], bfr[ni],
                                                                acc[mi][ni], 0, 0, 0);
    }
  }

  if (EPI == 2) {
    const int colo = ((int)blockIdx.x * 2 + wn) * 32 + c31;
#pragma unroll
    for (int mi = 0; mi < 4; mi++)
#pragma unroll
      for (int reg = 0; reg < 16; reg++) {
        const int row = m0 + wm * 128 + mi * 32 + (reg & 3) + 8 * (reg >> 2) + 4 * khalf;
        const float g = acc[mi][0][reg];
        const float u = acc[mi][1][reg];
        ((u16*)Cout)[(size_t)row * 4096 + colo] = f2bf(g / (1.f + __expf(-g)) * u);
      }
  } else {
#pragma unroll
    for (int mi = 0; mi < 4; mi++)
#pragma unroll
      for (int ni = 0; ni < 2; ni++) {
        const int col = n0 + wn * 64 + ni * 32 + c31;
#pragma unroll
        for (int reg = 0; reg < 16; reg++) {
          const int row = m0 + wm * 128 + mi * 32 + (reg & 3) + 8 * (reg >> 2) + 4 * khalf;
          ((u16*)Cout)[(size_t)row * N + col] = f2bf(acc[mi][ni][reg]);
        }
      }
  }
}

// ---------------------------------------------------------------------------
// Causal attention (strict k<q), softmax = exp(s)/(sum+1e-9), flash-style.
// q-tile 128 (wave owns 32 q rows), k-tile 64, double-buffered LDS staging of
// K [half][64][32] and V^T [khalf][64][32] via global_load_lds; one barrier
// per iter; P per-wave in XOR-swizzled LDS.
// ---------------------------------------------------------------------------
__global__ __launch_bounds__(256) void attn_kernel(const u16* __restrict__ qkv,
                                                   const u16* __restrict__ vT,
                                                   u16* __restrict__ av) {
  __shared__ u16 SM[2 * 8192];       // [buf][ K:2x64x32 | V:2x64x32 ]
  __shared__ u16 Ps[4 * 2048];       // per-wave P [32 q][64 k], 16B-chunk swizzle
  const int t = threadIdx.x, w = t >> 6, l = t & 63;
  const int lrow = l & 15, lk = l >> 4;
  const int bh = blockIdx.x;         // b*16 + h
  const int b = bh >> 4, h = bh & 15;
  const int qt = 15 - (int)blockIdx.y;   // heavy tiles dispatch first
  const int qbase = qt * 128 + w * 32;
  const int ktmax = 2 * qt + 1;
  u16* Pw = Ps + w * 2048;

  bf16x8 aq[2][2];
#pragma unroll
  for (int sub = 0; sub < 2; sub++)
#pragma unroll
    for (int half = 0; half < 2; half++)
      aq[sub][half] = *(const bf16x8*)(qkv + (size_t)(b * S_ + qbase + sub * 16 + lrow) * 3072 +
                                       h * 64 + half * 32 + lk * 8);

  const u16* gcur[4];
  int gstep[4], loff[4];
#pragma unroll
  for (int i = 0; i < 4; i++) {
    const int c = w + 4 * i;
    const int half = (c >> 2) & 1, grp = c & 3;
    if (c < 8) {
      gcur[i] = qkv + (size_t)(b * S_ + grp * 16 + (l >> 2)) * 3072 + D_ + h * 64 +
                half * 32 + (l & 3) * 8;
      gstep[i] = 64 * 3072;
      loff[i] = half * 2048 + grp * 512;
    } else {
      gcur[i] = vT + (size_t)(bh * 64 + grp * 16 + (l >> 2)) * S_ + half * 32 + (l & 3) * 8;
      gstep[i] = 64;
      loff[i] = 4096 + half * 2048 + grp * 512;
    }
  }

  floatx4 oacc[2][4] = {};
  float den[2][4] = {};

  int cur = 0;
#pragma unroll
  for (int i = 0; i < 4; i++) { gl_lds16(gcur[i], SM + loff[i]); gcur[i] += gstep[i]; }

  for (int kt = 0; kt <= ktmax; kt++) {
    __syncthreads();
    if (kt < ktmax) {
#pragma unroll
      for (int i = 0; i < 4; i++) {
        gl_lds16(gcur[i], SM + (cur ^ 1) * 8192 + loff[i]);
        gcur[i] += gstep[i];
      }
    }
    const u16* Kbuf = SM + cur * 8192;
    const u16* Vbuf = Kbuf + 4096;

    bf16x8 bk[4][2];
#pragma unroll
    for (int ct = 0; ct < 4; ct++)
#pragma unroll
      for (int half = 0; half < 2; half++)
        bk[ct][half] = *(const bf16x8*)(Kbuf + half * 2048 + (ct * 16 + lrow) * 32 + lk * 8);
    floatx4 sf[2][4] = {};
#pragma unroll
    for (int sub = 0; sub < 2; sub++)
#pragma unroll
      for (int ct = 0; ct < 4; ct++) {
        sf[sub][ct] = __builtin_amdgcn_mfma_f32_16x16x32_bf16(aq[sub][0], bk[ct][0],
                                                              sf[sub][ct], 0, 0, 0);
        sf[sub][ct] = __builtin_amdgcn_mfma_f32_16x16x32_bf16(aq[sub][1], bk[ct][1],
                                                              sf[sub][ct], 0, 0, 0);
      }

#pragma unroll
    for (int sub = 0; sub < 2; sub++)
#pragma unroll
      for (int ct = 0; ct < 4; ct++) {
        const int kpos = kt * 64 + ct * 16 + lrow;
#pragma unroll
        for (int r = 0; r < 4; r++) {
          const int qpos = qbase + sub * 16 + lk * 4 + r;
          const float p = (kpos < qpos) ? __expf(sf[sub][ct][r] * 0.125f) : 0.f;
          den[sub][r] += p;
          const int prow = sub * 16 + lk * 4 + r;
          const int pcol = ct * 16 + lrow;
          Pw[prow * 64 + ((((pcol >> 3) ^ (prow & 7))) << 3) + (pcol & 7)] = f2bf(p);
        }
      }

    bf16x8 ap[2][2], bv[4][2];
#pragma unroll
    for (int sub = 0; sub < 2; sub++)
#pragma unroll
      for (int kh = 0; kh < 2; kh++) {
        const int prow = sub * 16 + lrow;
        ap[sub][kh] = *(const bf16x8*)(Pw + prow * 64 + (((kh * 4 + lk) ^ (prow & 7)) << 3));
      }
#pragma unroll
    for (int ni = 0; ni < 4; ni++)
#pragma unroll
      for (int kh = 0; kh < 2; kh++)
        bv[ni][kh] = *(const bf16x8*)(Vbuf + kh * 2048 + (ni * 16 + lrow) * 32 + lk * 8);
#pragma unroll
    for (int sub = 0; sub < 2; sub++)
#pragma unroll
      for (int ni = 0; ni < 4; ni++) {
        oacc[sub][ni] = __builtin_amdgcn_mfma_f32_16x16x32_bf16(ap[sub][0], bv[ni][0],
                                                                oacc[sub][ni], 0, 0, 0);
        oacc[sub][ni] = __builtin_amdgcn_mfma_f32_16x16x32_bf16(ap[sub][1], bv[ni][1],
                                                                oacc[sub][ni], 0, 0, 0);
      }
    cur ^= 1;
  }

#pragma unroll
  for (int sub = 0; sub < 2; sub++)
#pragma unroll
    for (int r = 0; r < 4; r++) {
      float d = den[sub][r];
      d += __shfl_xor(d, 1);
      d += __shfl_xor(d, 2);
      d += __shfl_xor(d, 4);
      d += __shfl_xor(d, 8);
      den[sub][r] = d;
    }
#pragma unroll
  for (int sub = 0; sub < 2; sub++)
#pragma unroll
    for (int ni = 0; ni < 4; ni++)
#pragma unroll
      for (int r = 0; r < 4; r++) {
        const int row = qbase + sub * 16 + lk * 4 + r;
        const int col = h * 64 + ni * 16 + lrow;
        av[(size_t)(b * S_ + row) * 1024 + col] = f2bf(oacc[sub][ni][r] / (den[sub][r] + 1e-9f));
      }
}

// ---------------------------------------------------------------------------
// Workspace layout (bytes)
// ---------------------------------------------------------------------------
#define OFF_WQKV 0u            // [3072][1024] bf16
#define OFF_WO   6291456u      // [1024][1024] bf16
#define OFF_WGU  8388608u      // [8192][1024] bf16 (gate/up 32-col interleaved)
#define OFF_WDN  25165824u     // [1024][4096] bf16
#define OFF_H1   33554432u     // [4096][1024] bf16
#define OFF_QKV  41943040u     // [4096][3072] bf16
#define OFF_VT   67108864u     // [2][16][64][2048] bf16
#define OFF_AV   75497472u     // [4096][1024] bf16
#define OFF_X1   83886080u     // [4096][1024] f32
#define OFF_H2   100663296u    // [4096][1024] bf16
#define OFF_HID  109051904u    // [4096][4096] bf16

extern "C" void kernel_launch(void* const* d_in, const int* in_sizes, int n_in,
                              void* d_out, int out_size, void* d_ws, size_t ws_size,
                              hipStream_t stream) {
  const float* x      = (const float*)d_in[0];
  const float* w_q    = (const float*)d_in[1];
  const float* w_k    = (const float*)d_in[2];
  const float* w_v    = (const float*)d_in[3];
  const float* w_o    = (const float*)d_in[4];
  const float* w_gate = (const float*)d_in[5];
  const float* w_up   = (const float*)d_in[6];
  const float* w_down = (const float*)d_in[7];
  const float* g1     = (const float*)d_in[8];
  const float* g2     = (const float*)d_in[9];

  char* ws = (char*)d_ws;
  u16* wqkv_t = (u16*)(ws + OFF_WQKV);
  u16* wo_t   = (u16*)(ws + OFF_WO);
  u16* wgu_t  = (u16*)(ws + OFF_WGU);
  u16* wdn_t  = (u16*)(ws + OFF_WDN);
  u16* h1     = (u16*)(ws + OFF_H1);
  u16* qkv    = (u16*)(ws + OFF_QKV);
  u16* vT     = (u16*)(ws + OFF_VT);
  u16* av     = (u16*)(ws + OFF_AV);
  float* x1   = (float*)(ws + OFF_X1);
  u16* h2     = (u16*)(ws + OFF_H2);
  u16* hid    = (u16*)(ws + OFF_HID);
  float* out  = (float*)d_out;

  prep_weights<<<16384, dim3(32, 8), 0, stream>>>(w_q, w_k, w_v, w_o, w_gate, w_up, w_down,
                                                  wqkv_t, wo_t, wgu_t, wdn_t);

  rmsnorm_kernel<<<BS_, 256, 0, stream>>>(x, g1, h1);
  gemm_bt<128, 0><<<dim3(3072 / 128, BS_ / 128), 256, 0, stream>>>(h1, wqkv_t, qkv, nullptr,
                                                                   BS_, 3072, 1024);
  vtrans_kernel<<<dim3(S_ / 64, H_, B_), 256, 0, stream>>>(qkv, vT);
  attn_kernel<<<dim3(32, 16), 256, 0, stream>>>(qkv, vT, av);
  gemm_bt<64, 1><<<dim3(1024 / 64, BS_ / 128), 256, 0, stream>>>(av, wo_t, x1, x,
                                                                 BS_, 1024, 1024);
  rmsnorm_kernel<<<BS_, 256, 0, stream>>>(x1, g2, h2);
  gemm_big<2><<<dim3(8192 / 128, BS_ / 256), 256, 0, stream>>>(h2, wgu_t, hid,
                                                               BS_, 8192, 1024);
  gemm_bt<64, 1><<<dim3(1024 / 64, BS_ / 128), 256, 0, stream>>>(hid, wdn_t, out, x1,
                                                                 BS_, 1024, 4096);
}

// Round 6
// 392.938 us; speedup vs baseline: 1.0967x; 1.0117x over previous
//
#include <hip/hip_runtime.h>
#include <cstdint>
#include <cstddef>

typedef unsigned short u16;
typedef unsigned int u32;
typedef __bf16 bf16x8 __attribute__((ext_vector_type(8)));
typedef float floatx4 __attribute__((ext_vector_type(4)));
typedef float floatx16 __attribute__((ext_vector_type(16)));

#define B_ 2
#define S_ 2048
#define D_ 1024
#define H_ 16
#define DFF_ 4096
#define BS_ 4096   // B_*S_

__device__ __forceinline__ u16 f2bf(float f) {
  u32 u = __builtin_bit_cast(u32, f);
  u += 0x7fffu + ((u >> 16) & 1u);
  return (u16)(u >> 16);
}
__device__ __forceinline__ float bf2f(u16 h) {
  u32 u = ((u32)h) << 16;
  return __builtin_bit_cast(float, u);
}

// async global->LDS, 16B per lane; LDS dest is wave-uniform base + lane*16
__device__ __forceinline__ void gl_lds16(const u16* g, u16* l) {
  __builtin_amdgcn_global_load_lds(
      (const __attribute__((address_space(1))) void*)g,
      (__attribute__((address_space(3))) void*)l, 16, 0, 0);
}

// ---------------------------------------------------------------------------
// All weight transposes (+bf16 cast) in ONE kernel.  32x32 LDS tiles.
// mode 0: out row = col. mode 1/2 (gate/up): 32-col interleave ->
//   row' = (c>>5)*64 + (c&31) (+32 for up), so gemm waves see gate|up pairs.
// ---------------------------------------------------------------------------
__global__ void prep_weights(const float* __restrict__ wq, const float* __restrict__ wk,
                             const float* __restrict__ wv, const float* __restrict__ wo,
                             const float* __restrict__ wg, const float* __restrict__ wu,
                             const float* __restrict__ wd,
                             u16* __restrict__ wqkv_t, u16* __restrict__ wo_t,
                             u16* __restrict__ wgu_t, u16* __restrict__ wdn_t) {
  __shared__ float tile[32][33];
  const int id = blockIdx.x;
  const float* src;
  u16* dst;
  int R, C, bx, by, mode;
  if (id < 3072) {
    const int which = id >> 10, lo = id & 1023;
    src = which == 0 ? wq : (which == 1 ? wk : wv);
    dst = wqkv_t + which * 1024 * 1024;
    R = 1024; C = 1024; bx = lo & 31; by = lo >> 5; mode = 0;
  } else if (id < 4096) {
    const int lo = id - 3072;
    src = wo; dst = wo_t; R = 1024; C = 1024; bx = lo & 31; by = lo >> 5; mode = 0;
  } else if (id < 8192) {
    const int lo = id - 4096;
    src = wg; dst = wgu_t; R = 1024; C = 4096; bx = lo & 127; by = lo >> 7; mode = 1;
  } else if (id < 12288) {
    const int lo = id - 8192;
    src = wu; dst = wgu_t; R = 1024; C = 4096; bx = lo & 127; by = lo >> 7; mode = 2;
  } else {
    const int lo = id - 12288;
    src = wd; dst = wdn_t; R = 4096; C = 1024; bx = lo & 31; by = lo >> 5; mode = 0;
  }
  const int tx = threadIdx.x, ty = threadIdx.y;
  const int c0 = bx * 32, r0 = by * 32;
#pragma unroll
  for (int i = 0; i < 4; i++)
    tile[ty + i * 8][tx] = src[(size_t)(r0 + ty + i * 8) * C + c0 + tx];
  __syncthreads();
#pragma unroll
  for (int i = 0; i < 4; i++) {
    const int oc = c0 + ty + i * 8;
    const int orow = (mode == 0) ? oc
                                 : ((oc >> 5) * 64 + (oc & 31) + (mode == 2 ? 32 : 0));
    dst[(size_t)orow * R + r0 + tx] = f2bf(tile[tx][ty + i * 8]);
  }
}

// ---------------------------------------------------------------------------
// RMSNorm: x [rows][1024] f32, g [1024] f32 -> out bf16 [rows][1024]
// ---------------------------------------------------------------------------
__global__ __launch_bounds__(256) void rmsnorm_kernel(const float* __restrict__ x,
                                                      const float* __restrict__ g,
                                                      u16* __restrict__ out) {
  const int row = blockIdx.x, t = threadIdx.x;
  const float4 v = ((const float4*)(x + (size_t)row * 1024))[t];
  float ss = v.x * v.x + v.y * v.y + v.z * v.z + v.w * v.w;
#pragma unroll
  for (int off = 32; off > 0; off >>= 1) ss += __shfl_xor(ss, off);
  __shared__ float red[4];
  if ((t & 63) == 0) red[t >> 6] = ss;
  __syncthreads();
  ss = red[0] + red[1] + red[2] + red[3];
  const float inv = rsqrtf(ss * (1.0f / 1024.0f) + 1e-6f);
  const float4 gv = ((const float4*)g)[t];
  uint2 o;
  o.x = (u32)f2bf(v.x * inv * gv.x) | ((u32)f2bf(v.y * inv * gv.y) << 16);
  o.y = (u32)f2bf(v.z * inv * gv.z) | ((u32)f2bf(v.w * inv * gv.w) << 16);
  ((uint2*)(out + (size_t)row * 1024))[t] = o;
}

// ---------------------------------------------------------------------------
// V^T: qkv v-block [b,s,h,dv] -> vT [b][h][dv=64][S].  64x64 LDS tile.
// ---------------------------------------------------------------------------
__global__ __launch_bounds__(256) void vtrans_kernel(const u16* __restrict__ qkv,
                                                     u16* __restrict__ vT) {
  __shared__ u16 tile[64][72];
  const int t = threadIdx.x;
  const int s0 = blockIdx.x * 64, h = blockIdx.y, b = blockIdx.z;
  const int r = t >> 2, cc = t & 3;
  const u16* src = qkv + (size_t)(b * S_ + s0 + r) * 3072 + 2 * D_ + h * 64 + cc * 16;
  *(uint4*)(&tile[r][cc * 16]) = *(const uint4*)src;
  *(uint4*)(&tile[r][cc * 16 + 8]) = *(const uint4*)(src + 8);
  __syncthreads();
  union { uint4 u[2]; u16 s[16]; } o;
#pragma unroll
  for (int j = 0; j < 16; j++) o.s[j] = tile[cc * 16 + j][r];
  u16* dst = vT + (size_t)((b * H_ + h) * 64 + r) * S_ + s0 + cc * 16;
  *(uint4*)dst = o.u[0];
  *(uint4*)(dst + 8) = o.u[1];
}

// ---------------------------------------------------------------------------
// bf16 GEMM (R3-verified): C[M,N] = A[M,K] @ Bt[N,K]^T.
// 32x32x16 MFMA, BK=64, 128xBN tile, 4 waves (2x2), wave tile 64x(BN/2).
// EPI 0: bf16 out. EPI 1: f32 out + f32 residual.
// EPI 2 (BN=128): silu(gate)*up -> bf16 [M][4096], gate/up 32-col interleave.
// ---------------------------------------------------------------------------
template <int BN, int EPI>
__global__ __launch_bounds__(256) void gemm_bt(const u16* __restrict__ A,
                                               const u16* __restrict__ Bt,
                                               void* __restrict__ Cout,
                                               const float* __restrict__ res,
                                               int M, int N, int K) {
  __shared__ u16 As[128 * 64];
  __shared__ u16 Bs[BN * 64];
  constexpr int NTI = BN / 64;        // n-subtiles of 32 per wave
  constexpr int NSEG = 16 + BN / 8;   // 1024B staging segments
  constexpr int SPW = NSEG / 4;
  const int t = threadIdx.x, w = t >> 6, l = t & 63;
  const int m0 = blockIdx.y * 128, n0 = blockIdx.x * BN;
  const int wm = w >> 1, wn = w & 1;
  const int c31 = l & 31, khalf = l >> 5;

  const u16* gsrc[SPW];
  u16* ldst[SPW];
  {
    const int rl = l >> 3, ch = (l & 7) ^ rl;
#pragma unroll
    for (int i = 0; i < SPW; i++) {
      const int s = w * SPW + i;
      if (s < 16) {
        gsrc[i] = A + (size_t)(m0 + s * 8 + rl) * K + ch * 8;
        ldst[i] = As + s * 512;
      } else {
        gsrc[i] = Bt + (size_t)(n0 + (s - 16) * 8 + rl) * K + ch * 8;
        ldst[i] = Bs + (s - 16) * 512;
      }
    }
  }

  floatx16 acc[2][NTI] = {};

  for (int kk = 0; kk < K; kk += 64) {
    __syncthreads();
#pragma unroll
    for (int i = 0; i < SPW; i++) gl_lds16(gsrc[i], ldst[i]);
#pragma unroll
    for (int i = 0; i < SPW; i++) gsrc[i] += 64;
    __syncthreads();

#pragma unroll
    for (int ks = 0; ks < 4; ks++) {
      bf16x8 af[2], bfr[NTI];
#pragma unroll
      for (int mi = 0; mi < 2; mi++) {
        const int row = wm * 64 + mi * 32 + c31;
        const int e = (ks * 2 + khalf) ^ (row & 7);
        af[mi] = *(const bf16x8*)(As + row * 64 + e * 8);
      }
#pragma unroll
      for (int ni = 0; ni < NTI; ni++) {
        const int row = wn * (BN / 2) + ni * 32 + c31;
        const int e = (ks * 2 + khalf) ^ (row & 7);
        bfr[ni] = *(const bf16x8*)(Bs + row * 64 + e * 8);
      }
#pragma unroll
      for (int mi = 0; mi < 2; mi++)
#pragma unroll
        for (int ni = 0; ni < NTI; ni++)
          acc[mi][ni] = __builtin_amdgcn_mfma_f32_32x32x16_bf16(af[mi], bfr[ni],
                                                                acc[mi][ni], 0, 0, 0);
    }
  }

  // C/D layout (32x32): col = lane&31, row = (reg&3) + 8*(reg>>2) + 4*(lane>>5)
  if constexpr (EPI == 2) {
#pragma unroll
    for (int mi = 0; mi < 2; mi++) {
      const int colo = ((int)blockIdx.x * 2 + wn) * 32 + c31;
#pragma unroll
      for (int reg = 0; reg < 16; reg++) {
        const int row = m0 + wm * 64 + mi * 32 + (reg & 3) + 8 * (reg >> 2) + 4 * khalf;
        const float g = acc[mi][0][reg];
        const float u = acc[mi][NTI - 1][reg];
        ((u16*)Cout)[(size_t)row * 4096 + colo] = f2bf(g / (1.f + __expf(-g)) * u);
      }
    }
  } else {
#pragma unroll
    for (int mi = 0; mi < 2; mi++)
#pragma unroll
      for (int ni = 0; ni < NTI; ni++) {
        const int col = n0 + wn * (BN / 2) + ni * 32 + c31;
#pragma unroll
        for (int reg = 0; reg < 16; reg++) {
          const int row = m0 + wm * 64 + mi * 32 + (reg & 3) + 8 * (reg >> 2) + 4 * khalf;
          const size_t idx = (size_t)row * N + col;
          if (EPI == 0) ((u16*)Cout)[idx] = f2bf(acc[mi][ni][reg]);
          else          ((float*)Cout)[idx] = acc[mi][ni][reg] + res[idx];
        }
      }
  }
}

// ---------------------------------------------------------------------------
// Causal attention (strict k<q), softmax = exp(s)/(sum+1e-9), flash-style.
// q-tile 128 (wave owns 32 q rows), k-tile 64, double-buffered LDS staging via
// global_load_lds; one barrier per iter.
// S^T trick: mfma(K-frag, Q-frag) gives lane col=q (fixed), rows=4 consecutive
// k -> P stores become packed ds_write_b64 (8/iter vs 32 b16) and den is one
// scalar per lane (2 shfls at end + 8 bpermute broadcasts in epilogue).
// ---------------------------------------------------------------------------
__global__ __launch_bounds__(256) void attn_kernel(const u16* __restrict__ qkv,
                                                   const u16* __restrict__ vT,
                                                   u16* __restrict__ av) {
  __shared__ u16 SM[2 * 8192];       // [buf][ K:2x64x32 | V:2x64x32 ]
  __shared__ u16 Ps[4 * 2048];       // per-wave P [32 q][64 k], 16B-chunk swizzle
  const int t = threadIdx.x, w = t >> 6, l = t & 63;
  const int lrow = l & 15, lk = l >> 4;
  const int bh = blockIdx.x;         // b*16 + h
  const int b = bh >> 4, h = bh & 15;
  const int qt = 15 - (int)blockIdx.y;   // heavy tiles dispatch first
  const int qbase = qt * 128 + w * 32;
  const int ktmax = 2 * qt + 1;
  u16* Pw = Ps + w * 2048;

  bf16x8 aq[2][2];
#pragma unroll
  for (int sub = 0; sub < 2; sub++)
#pragma unroll
    for (int half = 0; half < 2; half++)
      aq[sub][half] = *(const bf16x8*)(qkv + (size_t)(b * S_ + qbase + sub * 16 + lrow) * 3072 +
                                       h * 64 + half * 32 + lk * 8);

  const u16* gcur[4];
  int gstep[4], loff[4];
#pragma unroll
  for (int i = 0; i < 4; i++) {
    const int c = w + 4 * i;
    const int half = (c >> 2) & 1, grp = c & 3;
    if (c < 8) {
      gcur[i] = qkv + (size_t)(b * S_ + grp * 16 + (l >> 2)) * 3072 + D_ + h * 64 +
                half * 32 + (l & 3) * 8;
      gstep[i] = 64 * 3072;
      loff[i] = half * 2048 + grp * 512;
    } else {
      gcur[i] = vT + (size_t)(bh * 64 + grp * 16 + (l >> 2)) * S_ + half * 32 + (l & 3) * 8;
      gstep[i] = 64;
      loff[i] = 4096 + half * 2048 + grp * 512;
    }
  }

  floatx4 oacc[2][4] = {};
  float den[2] = {0.f, 0.f};

  int cur = 0;
#pragma unroll
  for (int i = 0; i < 4; i++) { gl_lds16(gcur[i], SM + loff[i]); gcur[i] += gstep[i]; }

  for (int kt = 0; kt <= ktmax; kt++) {
    __syncthreads();
    if (kt < ktmax) {
#pragma unroll
      for (int i = 0; i < 4; i++) {
        gl_lds16(gcur[i], SM + (cur ^ 1) * 8192 + loff[i]);
        gcur[i] += gstep[i];
      }
    }
    const u16* Kbuf = SM + cur * 8192;
    const u16* Vbuf = Kbuf + 4096;

    bf16x8 bk[4][2];
#pragma unroll
    for (int ct = 0; ct < 4; ct++)
#pragma unroll
      for (int half = 0; half < 2; half++)
        bk[ct][half] = *(const bf16x8*)(Kbuf + half * 2048 + (ct * 16 + lrow) * 32 + lk * 8);

    // S^T = K Q^T : lane holds col=q=lrow (fixed), row=k_local=lk*4+r
    floatx4 sf[2][4] = {};
#pragma unroll
    for (int sub = 0; sub < 2; sub++)
#pragma unroll
      for (int ct = 0; ct < 4; ct++) {
        sf[sub][ct] = __builtin_amdgcn_mfma_f32_16x16x32_bf16(bk[ct][0], aq[sub][0],
                                                              sf[sub][ct], 0, 0, 0);
        sf[sub][ct] = __builtin_amdgcn_mfma_f32_16x16x32_bf16(bk[ct][1], aq[sub][1],
                                                              sf[sub][ct], 0, 0, 0);
      }

    // mask + exp -> packed P store (4 consecutive k per lane), den per lane
#pragma unroll
    for (int sub = 0; sub < 2; sub++) {
      const int qp = qbase + sub * 16 + lrow;
      const int prow = sub * 16 + lrow;
#pragma unroll
      for (int ct = 0; ct < 4; ct++) {
        const int kb = kt * 64 + ct * 16 + lk * 4;
        float p0 = (kb + 0 < qp) ? __expf(sf[sub][ct][0] * 0.125f) : 0.f;
        float p1 = (kb + 1 < qp) ? __expf(sf[sub][ct][1] * 0.125f) : 0.f;
        float p2 = (kb + 2 < qp) ? __expf(sf[sub][ct][2] * 0.125f) : 0.f;
        float p3 = (kb + 3 < qp) ? __expf(sf[sub][ct][3] * 0.125f) : 0.f;
        den[sub] += (p0 + p1) + (p2 + p3);
        uint2 pk;
        pk.x = (u32)f2bf(p0) | ((u32)f2bf(p1) << 16);
        pk.y = (u32)f2bf(p2) | ((u32)f2bf(p3) << 16);
        *(uint2*)(Pw + prow * 64 + (((2 * ct + (lk >> 1)) ^ (lrow & 7)) << 3) +
                  (lk & 1) * 4) = pk;
      }
    }

    bf16x8 ap[2][2], bv[4][2];
#pragma unroll
    for (int sub = 0; sub < 2; sub++)
#pragma unroll
      for (int kh = 0; kh < 2; kh++) {
        const int prow = sub * 16 + lrow;
        ap[sub][kh] = *(const bf16x8*)(Pw + prow * 64 + (((kh * 4 + lk) ^ (prow & 7)) << 3));
      }
#pragma unroll
    for (int ni = 0; ni < 4; ni++)
#pragma unroll
      for (int kh = 0; kh < 2; kh++)
        bv[ni][kh] = *(const bf16x8*)(Vbuf + kh * 2048 + (ni * 16 + lrow) * 32 + lk * 8);
#pragma unroll
    for (int sub = 0; sub < 2; sub++)
#pragma unroll
      for (int ni = 0; ni < 4; ni++) {
        oacc[sub][ni] = __builtin_amdgcn_mfma_f32_16x16x32_bf16(ap[sub][0], bv[ni][0],
                                                                oacc[sub][ni], 0, 0, 0);
        oacc[sub][ni] = __builtin_amdgcn_mfma_f32_16x16x32_bf16(ap[sub][1], bv[ni][1],
                                                                oacc[sub][ni], 0, 0, 0);
      }
    cur ^= 1;
  }

  // den: reduce across the 4 quads (lane now holds full den for q = lrow)
#pragma unroll
  for (int sub = 0; sub < 2; sub++) {
    den[sub] += __shfl_xor(den[sub], 16);
    den[sub] += __shfl_xor(den[sub], 32);
  }
  // broadcast den to the oacc row mapping (row = lk*4 + r lives in lane lk*4+r)
  float dq[2][4];
#pragma unroll
  for (int sub = 0; sub < 2; sub++)
#pragma unroll
    for (int r = 0; r < 4; r++)
      dq[sub][r] = __shfl(den[sub], lk * 4 + r);

#pragma unroll
  for (int sub = 0; sub < 2; sub++)
#pragma unroll
    for (int ni = 0; ni < 4; ni++)
#pragma unroll
      for (int r = 0; r < 4; r++) {
        const int row = qbase + sub * 16 + lk * 4 + r;
        const int col = h * 64 + ni * 16 + lrow;
        av[(size_t)(b * S_ + row) * 1024 + col] = f2bf(oacc[sub][ni][r] / (dq[sub][r] + 1e-9f));
      }
}

// ---------------------------------------------------------------------------
// Workspace layout (bytes)
// ---------------------------------------------------------------------------
#define OFF_WQKV 0u            // [3072][1024] bf16
#define OFF_WO   6291456u      // [1024][1024] bf16
#define OFF_WGU  8388608u      // [8192][1024] bf16 (gate/up 32-col interleaved)
#define OFF_WDN  25165824u     // [1024][4096] bf16
#define OFF_H1   33554432u     // [4096][1024] bf16
#define OFF_QKV  41943040u     // [4096][3072] bf16
#define OFF_VT   67108864u     // [2][16][64][2048] bf16
#define OFF_AV   75497472u     // [4096][1024] bf16
#define OFF_X1   83886080u     // [4096][1024] f32
#define OFF_H2   100663296u    // [4096][1024] bf16
#define OFF_HID  109051904u    // [4096][4096] bf16

extern "C" void kernel_launch(void* const* d_in, const int* in_sizes, int n_in,
                              void* d_out, int out_size, void* d_ws, size_t ws_size,
                              hipStream_t stream) {
  const float* x      = (const float*)d_in[0];
  const float* w_q    = (const float*)d_in[1];
  const float* w_k    = (const float*)d_in[2];
  const float* w_v    = (const float*)d_in[3];
  const float* w_o    = (const float*)d_in[4];
  const float* w_gate = (const float*)d_in[5];
  const float* w_up   = (const float*)d_in[6];
  const float* w_down = (const float*)d_in[7];
  const float* g1     = (const float*)d_in[8];
  const float* g2     = (const float*)d_in[9];

  char* ws = (char*)d_ws;
  u16* wqkv_t = (u16*)(ws + OFF_WQKV);
  u16* wo_t   = (u16*)(ws + OFF_WO);
  u16* wgu_t  = (u16*)(ws + OFF_WGU);
  u16* wdn_t  = (u16*)(ws + OFF_WDN);
  u16* h1     = (u16*)(ws + OFF_H1);
  u16* qkv    = (u16*)(ws + OFF_QKV);
  u16* vT     = (u16*)(ws + OFF_VT);
  u16* av     = (u16*)(ws + OFF_AV);
  float* x1   = (float*)(ws + OFF_X1);
  u16* h2     = (u16*)(ws + OFF_H2);
  u16* hid    = (u16*)(ws + OFF_HID);
  float* out  = (float*)d_out;

  prep_weights<<<16384, dim3(32, 8), 0, stream>>>(w_q, w_k, w_v, w_o, w_gate, w_up, w_down,
                                                  wqkv_t, wo_t, wgu_t, wdn_t);

  rmsnorm_kernel<<<BS_, 256, 0, stream>>>(x, g1, h1);
  gemm_bt<128, 0><<<dim3(3072 / 128, BS_ / 128), 256, 0, stream>>>(h1, wqkv_t, qkv, nullptr,
                                                                   BS_, 3072, 1024);
  vtrans_kernel<<<dim3(S_ / 64, H_, B_), 256, 0, stream>>>(qkv, vT);
  attn_kernel<<<dim3(32, 16), 256, 0, stream>>>(qkv, vT, av);
  gemm_bt<64, 1><<<dim3(1024 / 64, BS_ / 128), 256, 0, stream>>>(av, wo_t, x1, x,
                                                                 BS_, 1024, 1024);
  rmsnorm_kernel<<<BS_, 256, 0, stream>>>(x1, g2, h2);
  gemm_bt<128, 2><<<dim3(8192 / 128, BS_ / 128), 256, 0, stream>>>(h2, wgu_t, hid, nullptr,
                                                                   BS_, 8192, 1024);
  gemm_bt<64, 1><<<dim3(1024 / 64, BS_ / 128), 256, 0, stream>>>(hid, wdn_t, out, x1,
                                                                 BS_, 1024, 4096);
}

// Round 7
// 349.166 us; speedup vs baseline: 1.2342x; 1.1254x over previous
//
#include <hip/hip_runtime.h>
#include <cstdint>
#include <cstddef>

typedef unsigned short u16;
typedef unsigned char u8;
typedef unsigned int u32;
typedef __bf16 bf16x8 __attribute__((ext_vector_type(8)));
typedef float floatx4 __attribute__((ext_vector_type(4)));
typedef float floatx16 __attribute__((ext_vector_type(16)));
typedef int i32x8 __attribute__((ext_vector_type(8)));

#define B_ 2
#define S_ 2048
#define D_ 1024
#define H_ 16
#define DFF_ 4096
#define BS_ 4096   // B_*S_

__device__ __forceinline__ u16 f2bf(float f) {
  u32 u = __builtin_bit_cast(u32, f);
  u += 0x7fffu + ((u >> 16) & 1u);
  return (u16)(u >> 16);
}
__device__ __forceinline__ float bf2f(u16 h) {
  u32 u = ((u32)h) << 16;
  return __builtin_bit_cast(float, u);
}

// f32 -> OCP e4m3 (RNE, flush <2^-6 to 0, clamp to 448). Manual bit-twiddle
// (no reliance on cvt builtins). Subnormal flush is fine: inputs are
// pre-scaled so |x|<2^-6 contributes negligibly.
__device__ __forceinline__ u32 f2e4m3(float f) {
  u32 u = __builtin_bit_cast(u32, f);
  const u32 s = (u >> 24) & 0x80u;
  const u32 au = u & 0x7fffffffu;
  if (au < 0x3c800000u) return s;           // |x| < 2^-6 -> signed zero
  if (au > 0x43e00000u) return s | 0x7eu;   // clamp to 448
  const u32 lsb = (au >> 20) & 1u;
  const u32 r = au + 0x0007ffffu + lsb;     // RNE to 3 mantissa bits
  const u32 e = (r >> 23) & 0xffu;
  const u32 m = (r >> 20) & 7u;
  return s | (((e - 120u) & 0xfu) << 3) | m;
}

// async global->LDS, 16B per lane; LDS dest is wave-uniform base + lane*16
__device__ __forceinline__ void gl_lds16(const void* g, void* l) {
  __builtin_amdgcn_global_load_lds(
      (const __attribute__((address_space(1))) void*)g,
      (__attribute__((address_space(3))) void*)l, 16, 0, 0);
}

// ---------------------------------------------------------------------------
// All weight transposes (+cast) in ONE kernel.  32x32 LDS tiles.
// mode 0 (bf16): out row = col, vectorized uint2 stores.
// mode 1/2 (gate/up): fp8 e4m3 output, weights pre-scaled by 2^6 (the fp8
//   GEMM dequants via MX scale 2^-6); rows 32-col interleaved:
//   row' = (c>>5)*64 + (c&31) (+32 for up).
// ---------------------------------------------------------------------------
__global__ void prep_weights(const float* __restrict__ wq, const float* __restrict__ wk,
                             const float* __restrict__ wv, const float* __restrict__ wo,
                             const float* __restrict__ wg, const float* __restrict__ wu,
                             const float* __restrict__ wd,
                             u16* __restrict__ wqkv_t, u16* __restrict__ wo_t,
                             u8* __restrict__ wguf8, u16* __restrict__ wdn_t) {
  __shared__ float tile[32][33];
  const int id = blockIdx.x;
  const float* src;
  u16* dst = nullptr;
  int R, C, bx, by, mode;
  if (id < 3072) {
    const int which = id >> 10, lo = id & 1023;
    src = which == 0 ? wq : (which == 1 ? wk : wv);
    dst = wqkv_t + which * 1024 * 1024;
    R = 1024; C = 1024; bx = lo & 31; by = lo >> 5; mode = 0;
  } else if (id < 4096) {
    const int lo = id - 3072;
    src = wo; dst = wo_t; R = 1024; C = 1024; bx = lo & 31; by = lo >> 5; mode = 0;
  } else if (id < 8192) {
    const int lo = id - 4096;
    src = wg; R = 1024; C = 4096; bx = lo & 127; by = lo >> 7; mode = 1;
  } else if (id < 12288) {
    const int lo = id - 8192;
    src = wu; R = 1024; C = 4096; bx = lo & 127; by = lo >> 7; mode = 2;
  } else {
    const int lo = id - 12288;
    src = wd; dst = wdn_t; R = 4096; C = 1024; bx = lo & 31; by = lo >> 5; mode = 0;
  }
  const int tx = threadIdx.x, ty = threadIdx.y;
  const int c0 = bx * 32, r0 = by * 32;
#pragma unroll
  for (int i = 0; i < 4; i++)
    tile[ty + i * 8][tx] = src[(size_t)(r0 + ty + i * 8) * C + c0 + tx];
  __syncthreads();
  // store phase: thread sx handles output col oc = c0+(sx>>3), rows r0+cg..+3
  const int sx = ty * 32 + tx;
  const int oci = sx >> 3, cg = (sx & 7) * 4;
  const int oc = c0 + oci;
  const float v0 = tile[cg][oci], v1 = tile[cg + 1][oci];
  const float v2 = tile[cg + 2][oci], v3 = tile[cg + 3][oci];
  if (mode == 0) {
    uint2 o;
    o.x = (u32)f2bf(v0) | ((u32)f2bf(v1) << 16);
    o.y = (u32)f2bf(v2) | ((u32)f2bf(v3) << 16);
    *(uint2*)(dst + (size_t)oc * R + r0 + cg) = o;
  } else {
    const int orow = (oc >> 5) * 64 + (oc & 31) + (mode == 2 ? 32 : 0);
    const u32 p = f2e4m3(v0 * 64.f) | (f2e4m3(v1 * 64.f) << 8) |
                  (f2e4m3(v2 * 64.f) << 16) | (f2e4m3(v3 * 64.f) << 24);
    *(u32*)(wguf8 + (size_t)orow * 1024 + r0 + cg) = p;
  }
}

// ---------------------------------------------------------------------------
// RMSNorm: x [rows][1024] f32, g [1024] f32 -> bf16 (F8=0) or fp8 e4m3 (F8=1)
// ---------------------------------------------------------------------------
template <int F8>
__global__ __launch_bounds__(256) void rmsnorm_kernel(const float* __restrict__ x,
                                                      const float* __restrict__ g,
                                                      void* __restrict__ out) {
  const int row = blockIdx.x, t = threadIdx.x;
  const float4 v = ((const float4*)(x + (size_t)row * 1024))[t];
  float ss = v.x * v.x + v.y * v.y + v.z * v.z + v.w * v.w;
#pragma unroll
  for (int off = 32; off > 0; off >>= 1) ss += __shfl_xor(ss, off);
  __shared__ float red[4];
  if ((t & 63) == 0) red[t >> 6] = ss;
  __syncthreads();
  ss = red[0] + red[1] + red[2] + red[3];
  const float inv = rsqrtf(ss * (1.0f / 1024.0f) + 1e-6f);
  const float4 gv = ((const float4*)g)[t];
  const float y0 = v.x * inv * gv.x, y1 = v.y * inv * gv.y;
  const float y2 = v.z * inv * gv.z, y3 = v.w * inv * gv.w;
  if (F8) {
    const u32 p = f2e4m3(y0) | (f2e4m3(y1) << 8) | (f2e4m3(y2) << 16) | (f2e4m3(y3) << 24);
    ((u32*)out)[(size_t)row * 256 + t] = p;
  } else {
    uint2 o;
    o.x = (u32)f2bf(y0) | ((u32)f2bf(y1) << 16);
    o.y = (u32)f2bf(y2) | ((u32)f2bf(y3) << 16);
    ((uint2*)out)[(size_t)row * 256 + t] = o;
  }
}

// ---------------------------------------------------------------------------
// bf16 GEMM (R3-verified): C[M,N] = A[M,K] @ Bt[N,K]^T.
// 32x32x16 MFMA, BK=64, 128xBN tile, 4 waves (2x2), wave tile 64x(BN/2).
// EPI 0: bf16 out. EPI 1: f32 out + f32 residual.
// EPI 3 (qkv): n0<2048 -> bf16 qkv out; n0>=2048 (V cols) -> write vT
//   [b][h][dv][S] directly (packed b64, 4 consecutive s per store) and skip
//   the dead qkv V-region.
// ---------------------------------------------------------------------------
template <int BN, int EPI>
__global__ __launch_bounds__(256) void gemm_bt(const u16* __restrict__ A,
                                               const u16* __restrict__ Bt,
                                               void* __restrict__ Cout,
                                               const float* __restrict__ res,
                                               u16* __restrict__ vTout,
                                               int M, int N, int K) {
  __shared__ u16 As[128 * 64];
  __shared__ u16 Bs[BN * 64];
  constexpr int NTI = BN / 64;        // n-subtiles of 32 per wave
  constexpr int NSEG = 16 + BN / 8;   // 1024B staging segments
  constexpr int SPW = NSEG / 4;
  const int t = threadIdx.x, w = t >> 6, l = t & 63;
  const int m0 = blockIdx.y * 128, n0 = blockIdx.x * BN;
  const int wm = w >> 1, wn = w & 1;
  const int c31 = l & 31, khalf = l >> 5;

  const u16* gsrc[SPW];
  u16* ldst[SPW];
  {
    const int rl = l >> 3, ch = (l & 7) ^ rl;
#pragma unroll
    for (int i = 0; i < SPW; i++) {
      const int s = w * SPW + i;
      if (s < 16) {
        gsrc[i] = A + (size_t)(m0 + s * 8 + rl) * K + ch * 8;
        ldst[i] = As + s * 512;
      } else {
        gsrc[i] = Bt + (size_t)(n0 + (s - 16) * 8 + rl) * K + ch * 8;
        ldst[i] = Bs + (s - 16) * 512;
      }
    }
  }

  floatx16 acc[2][NTI] = {};

  for (int kk = 0; kk < K; kk += 64) {
    __syncthreads();
#pragma unroll
    for (int i = 0; i < SPW; i++) gl_lds16(gsrc[i], ldst[i]);
#pragma unroll
    for (int i = 0; i < SPW; i++) gsrc[i] += 64;
    __syncthreads();

#pragma unroll
    for (int ks = 0; ks < 4; ks++) {
      bf16x8 af[2], bfr[NTI];
#pragma unroll
      for (int mi = 0; mi < 2; mi++) {
        const int row = wm * 64 + mi * 32 + c31;
        const int e = (ks * 2 + khalf) ^ (row & 7);
        af[mi] = *(const bf16x8*)(As + row * 64 + e * 8);
      }
#pragma unroll
      for (int ni = 0; ni < NTI; ni++) {
        const int row = wn * (BN / 2) + ni * 32 + c31;
        const int e = (ks * 2 + khalf) ^ (row & 7);
        bfr[ni] = *(const bf16x8*)(Bs + row * 64 + e * 8);
      }
#pragma unroll
      for (int mi = 0; mi < 2; mi++)
#pragma unroll
        for (int ni = 0; ni < NTI; ni++)
          acc[mi][ni] = __builtin_amdgcn_mfma_f32_32x32x16_bf16(af[mi], bfr[ni],
                                                                acc[mi][ni], 0, 0, 0);
    }
  }

  // C/D layout (32x32): col = lane&31, row = (reg&3) + 8*(reg>>2) + 4*(lane>>5)
  if constexpr (EPI == 3) {
    if (n0 >= 2048) {
#pragma unroll
      for (int mi = 0; mi < 2; mi++)
#pragma unroll
        for (int ni = 0; ni < NTI; ni++) {
          const int col = n0 + wn * (BN / 2) + ni * 32 + c31 - 2048;
          const int hh = col >> 6, dv = col & 63;
          const int rbase = m0 + wm * 64 + mi * 32 + 4 * khalf;
          const int bb = rbase >> 11;
          u16* vp = vTout + (size_t)((bb * 16 + hh) * 64 + dv) * 2048 + (rbase & 2047);
#pragma unroll
          for (int rg = 0; rg < 4; rg++) {
            uint2 pk;
            pk.x = (u32)f2bf(acc[mi][ni][rg * 4 + 0]) |
                   ((u32)f2bf(acc[mi][ni][rg * 4 + 1]) << 16);
            pk.y = (u32)f2bf(acc[mi][ni][rg * 4 + 2]) |
                   ((u32)f2bf(acc[mi][ni][rg * 4 + 3]) << 16);
            *(uint2*)(vp + rg * 8) = pk;
          }
        }
      return;
    }
  }
#pragma unroll
  for (int mi = 0; mi < 2; mi++)
#pragma unroll
    for (int ni = 0; ni < NTI; ni++) {
      const int col = n0 + wn * (BN / 2) + ni * 32 + c31;
#pragma unroll
      for (int reg = 0; reg < 16; reg++) {
        const int row = m0 + wm * 64 + mi * 32 + (reg & 3) + 8 * (reg >> 2) + 4 * khalf;
        const size_t idx = (size_t)row * N + col;
        if (EPI == 1) ((float*)Cout)[idx] = acc[mi][ni][reg] + res[idx];
        else          ((u16*)Cout)[idx] = f2bf(acc[mi][ni][reg]);
      }
    }
}

// ---------------------------------------------------------------------------
// MX-fp8 gate/up GEMM: hid = silu(h2 @ Wg) * (h2 @ Wu), fp8 e4m3 operands.
// mfma_scale_f32_32x32x64_f8f6f4, static scales: A=2^0 (0x7F), B=2^-6 (0x79,
// weights pre-scaled 2^6 at cast).  128x128 tile, BK=64 bytes, 4 waves 2x2.
// LDS: [row][64B] with 16B-chunk XOR swizzle c^((row>>1)&3) -> stride-1-
// equivalent bank distribution for the 2xb128 fragment reads.
// B rows gate/up 32-col interleaved: ni=0 gate, ni=1 up.
// ---------------------------------------------------------------------------
__global__ __launch_bounds__(256) void gemm_f8(const u8* __restrict__ A,
                                               const u8* __restrict__ B,
                                               u16* __restrict__ hid,
                                               int M, int K) {
  __shared__ u8 As[128 * 64];
  __shared__ u8 Bs[128 * 64];
  const int t = threadIdx.x, w = t >> 6, l = t & 63;
  const int m0 = blockIdx.y * 128, n0 = blockIdx.x * 128;
  const int wm = w >> 1, wn = w & 1;
  const int c31 = l & 31, hf = l >> 5;

  // staging: 16 segs of 1KB (A:8, B:8), 4 per wave; lane j: row j>>2,
  // fetches global chunk (j&3)^((j>>3)&3) so LDS pos p holds chunk p^((row>>1)&3)
  const u8* gsrc[4];
  u8* ldst[4];
  {
    const int rl = l >> 2, ch = (l & 3) ^ ((l >> 3) & 3);
#pragma unroll
    for (int i = 0; i < 4; i++) {
      const int s = w * 4 + i;
      if (s < 8) {
        gsrc[i] = A + (size_t)(m0 + s * 16 + rl) * K + ch * 16;
        ldst[i] = As + s * 1024;
      } else {
        gsrc[i] = B + (size_t)(n0 + (s - 8) * 16 + rl) * K + ch * 16;
        ldst[i] = Bs + (s - 8) * 1024;
      }
    }
  }

  floatx16 acc[2][2] = {};

  for (int kk = 0; kk < K; kk += 64) {
    __syncthreads();
#pragma unroll
    for (int i = 0; i < 4; i++) gl_lds16(gsrc[i] + kk, ldst[i]);
    __syncthreads();

    i32x8 af[2], bf[2];
#pragma unroll
    for (int mi = 0; mi < 2; mi++) {
      const int r = wm * 64 + mi * 32 + c31;
      const int g = (r >> 1) & 3;
      const uint4 lo = *(const uint4*)(As + r * 64 + ((2 * hf) ^ g) * 16);
      const uint4 hi = *(const uint4*)(As + r * 64 + ((2 * hf + 1) ^ g) * 16);
      af[mi] = i32x8{(int)lo.x, (int)lo.y, (int)lo.z, (int)lo.w,
                     (int)hi.x, (int)hi.y, (int)hi.z, (int)hi.w};
    }
#pragma unroll
    for (int ni = 0; ni < 2; ni++) {
      const int r = wn * 64 + ni * 32 + c31;
      const int g = (r >> 1) & 3;
      const uint4 lo = *(const uint4*)(Bs + r * 64 + ((2 * hf) ^ g) * 16);
      const uint4 hi = *(const uint4*)(Bs + r * 64 + ((2 * hf + 1) ^ g) * 16);
      bf[ni] = i32x8{(int)lo.x, (int)lo.y, (int)lo.z, (int)lo.w,
                     (int)hi.x, (int)hi.y, (int)hi.z, (int)hi.w};
    }
#pragma unroll
    for (int mi = 0; mi < 2; mi++)
#pragma unroll
      for (int ni = 0; ni < 2; ni++)
        acc[mi][ni] = __builtin_amdgcn_mfma_scale_f32_32x32x64_f8f6f4(
            af[mi], bf[ni], acc[mi][ni], 0, 0,
            0, 0x7F7F7F7F,   // A scale = 2^0
            0, 0x79797979);  // B scale = 2^-6
  }

  // C/D: col = lane&31, row = (reg&3) + 8*(reg>>2) + 4*(lane>>5)
#pragma unroll
  for (int mi = 0; mi < 2; mi++) {
    const int colo = ((int)blockIdx.x * 2 + wn) * 32 + c31;
#pragma unroll
    for (int reg = 0; reg < 16; reg++) {
      const int row = m0 + wm * 64 + mi * 32 + (reg & 3) + 8 * (reg >> 2) + 4 * hf;
      const float g = acc[mi][0][reg];
      const float u = acc[mi][1][reg];
      hid[(size_t)row * 4096 + colo] = f2bf(g / (1.f + __expf(-g)) * u);
    }
  }
}

// ---------------------------------------------------------------------------
// Causal attention (strict k<q), softmax = exp(s)/(sum+1e-9), flash-style.
// (unchanged from R6: S^T trick, packed b64 P stores, scalar den per lane)
// ---------------------------------------------------------------------------
__global__ __launch_bounds__(256) void attn_kernel(const u16* __restrict__ qkv,
                                                   const u16* __restrict__ vT,
                                                   u16* __restrict__ av) {
  __shared__ u16 SM[2 * 8192];
  __shared__ u16 Ps[4 * 2048];
  const int t = threadIdx.x, w = t >> 6, l = t & 63;
  const int lrow = l & 15, lk = l >> 4;
  const int bh = blockIdx.x;
  const int b = bh >> 4, h = bh & 15;
  const int qt = 15 - (int)blockIdx.y;
  const int qbase = qt * 128 + w * 32;
  const int ktmax = 2 * qt + 1;
  u16* Pw = Ps + w * 2048;

  bf16x8 aq[2][2];
#pragma unroll
  for (int sub = 0; sub < 2; sub++)
#pragma unroll
    for (int half = 0; half < 2; half++)
      aq[sub][half] = *(const bf16x8*)(qkv + (size_t)(b * S_ + qbase + sub * 16 + lrow) * 3072 +
                                       h * 64 + half * 32 + lk * 8);

  const u16* gcur[4];
  int gstep[4], loff[4];
#pragma unroll
  for (int i = 0; i < 4; i++) {
    const int c = w + 4 * i;
    const int half = (c >> 2) & 1, grp = c & 3;
    if (c < 8) {
      gcur[i] = qkv + (size_t)(b * S_ + grp * 16 + (l >> 2)) * 3072 + D_ + h * 64 +
                half * 32 + (l & 3) * 8;
      gstep[i] = 64 * 3072;
      loff[i] = half * 2048 + grp * 512;
    } else {
      gcur[i] = vT + (size_t)(bh * 64 + grp * 16 + (l >> 2)) * S_ + half * 32 + (l & 3) * 8;
      gstep[i] = 64;
      loff[i] = 4096 + half * 2048 + grp * 512;
    }
  }

  floatx4 oacc[2][4] = {};
  float den[2] = {0.f, 0.f};

  int cur = 0;
#pragma unroll
  for (int i = 0; i < 4; i++) { gl_lds16(gcur[i], SM + loff[i]); gcur[i] += gstep[i]; }

  for (int kt = 0; kt <= ktmax; kt++) {
    __syncthreads();
    if (kt < ktmax) {
#pragma unroll
      for (int i = 0; i < 4; i++) {
        gl_lds16(gcur[i], SM + (cur ^ 1) * 8192 + loff[i]);
        gcur[i] += gstep[i];
      }
    }
    const u16* Kbuf = SM + cur * 8192;
    const u16* Vbuf = Kbuf + 4096;

    bf16x8 bk[4][2];
#pragma unroll
    for (int ct = 0; ct < 4; ct++)
#pragma unroll
      for (int half = 0; half < 2; half++)
        bk[ct][half] = *(const bf16x8*)(Kbuf + half * 2048 + (ct * 16 + lrow) * 32 + lk * 8);

    floatx4 sf[2][4] = {};
#pragma unroll
    for (int sub = 0; sub < 2; sub++)
#pragma unroll
      for (int ct = 0; ct < 4; ct++) {
        sf[sub][ct] = __builtin_amdgcn_mfma_f32_16x16x32_bf16(bk[ct][0], aq[sub][0],
                                                              sf[sub][ct], 0, 0, 0);
        sf[sub][ct] = __builtin_amdgcn_mfma_f32_16x16x32_bf16(bk[ct][1], aq[sub][1],
                                                              sf[sub][ct], 0, 0, 0);
      }

#pragma unroll
    for (int sub = 0; sub < 2; sub++) {
      const int qp = qbase + sub * 16 + lrow;
      const int prow = sub * 16 + lrow;
#pragma unroll
      for (int ct = 0; ct < 4; ct++) {
        const int kb = kt * 64 + ct * 16 + lk * 4;
        float p0 = (kb + 0 < qp) ? __expf(sf[sub][ct][0] * 0.125f) : 0.f;
        float p1 = (kb + 1 < qp) ? __expf(sf[sub][ct][1] * 0.125f) : 0.f;
        float p2 = (kb + 2 < qp) ? __expf(sf[sub][ct][2] * 0.125f) : 0.f;
        float p3 = (kb + 3 < qp) ? __expf(sf[sub][ct][3] * 0.125f) : 0.f;
        den[sub] += (p0 + p1) + (p2 + p3);
        uint2 pk;
        pk.x = (u32)f2bf(p0) | ((u32)f2bf(p1) << 16);
        pk.y = (u32)f2bf(p2) | ((u32)f2bf(p3) << 16);
        *(uint2*)(Pw + prow * 64 + (((2 * ct + (lk >> 1)) ^ (lrow & 7)) << 3) +
                  (lk & 1) * 4) = pk;
      }
    }

    bf16x8 ap[2][2], bv[4][2];
#pragma unroll
    for (int sub = 0; sub < 2; sub++)
#pragma unroll
      for (int kh = 0; kh < 2; kh++) {
        const int prow = sub * 16 + lrow;
        ap[sub][kh] = *(const bf16x8*)(Pw + prow * 64 + (((kh * 4 + lk) ^ (prow & 7)) << 3));
      }
#pragma unroll
    for (int ni = 0; ni < 4; ni++)
#pragma unroll
      for (int kh = 0; kh < 2; kh++)
        bv[ni][kh] = *(const bf16x8*)(Vbuf + kh * 2048 + (ni * 16 + lrow) * 32 + lk * 8);
#pragma unroll
    for (int sub = 0; sub < 2; sub++)
#pragma unroll
      for (int ni = 0; ni < 4; ni++) {
        oacc[sub][ni] = __builtin_amdgcn_mfma_f32_16x16x32_bf16(ap[sub][0], bv[ni][0],
                                                                oacc[sub][ni], 0, 0, 0);
        oacc[sub][ni] = __builtin_amdgcn_mfma_f32_16x16x32_bf16(ap[sub][1], bv[ni][1],
                                                                oacc[sub][ni], 0, 0, 0);
      }
    cur ^= 1;
  }

#pragma unroll
  for (int sub = 0; sub < 2; sub++) {
    den[sub] += __shfl_xor(den[sub], 16);
    den[sub] += __shfl_xor(den[sub], 32);
  }
  float dq[2][4];
#pragma unroll
  for (int sub = 0; sub < 2; sub++)
#pragma unroll
    for (int r = 0; r < 4; r++)
      dq[sub][r] = __shfl(den[sub], lk * 4 + r);

#pragma unroll
  for (int sub = 0; sub < 2; sub++)
#pragma unroll
    for (int ni = 0; ni < 4; ni++)
#pragma unroll
      for (int r = 0; r < 4; r++) {
        const int row = qbase + sub * 16 + lk * 4 + r;
        const int col = h * 64 + ni * 16 + lrow;
        av[(size_t)(b * S_ + row) * 1024 + col] = f2bf(oacc[sub][ni][r] / (dq[sub][r] + 1e-9f));
      }
}

// ---------------------------------------------------------------------------
// Workspace layout (bytes)
// ---------------------------------------------------------------------------
#define OFF_WQKV 0u            // [3072][1024] bf16
#define OFF_WO   6291456u      // [1024][1024] bf16
#define OFF_WGU8 8388608u      // [8192][1024] fp8 (gate/up 32-col interleaved, x64)
#define OFF_WDN  16777216u     // [1024][4096] bf16
#define OFF_H1   25165824u     // [4096][1024] bf16
#define OFF_QKV  33554432u     // [4096][3072] bf16 (V region unused)
#define OFF_VT   58720256u     // [2][16][64][2048] bf16
#define OFF_AV   67108864u     // [4096][1024] bf16
#define OFF_X1   75497472u     // [4096][1024] f32
#define OFF_H2F8 92274688u     // [4096][1024] fp8
#define OFF_HID  96468992u     // [4096][4096] bf16

extern "C" void kernel_launch(void* const* d_in, const int* in_sizes, int n_in,
                              void* d_out, int out_size, void* d_ws, size_t ws_size,
                              hipStream_t stream) {
  const float* x      = (const float*)d_in[0];
  const float* w_q    = (const float*)d_in[1];
  const float* w_k    = (const float*)d_in[2];
  const float* w_v    = (const float*)d_in[3];
  const float* w_o    = (const float*)d_in[4];
  const float* w_gate = (const float*)d_in[5];
  const float* w_up   = (const float*)d_in[6];
  const float* w_down = (const float*)d_in[7];
  const float* g1     = (const float*)d_in[8];
  const float* g2     = (const float*)d_in[9];

  char* ws = (char*)d_ws;
  u16* wqkv_t = (u16*)(ws + OFF_WQKV);
  u16* wo_t   = (u16*)(ws + OFF_WO);
  u8*  wguf8  = (u8*)(ws + OFF_WGU8);
  u16* wdn_t  = (u16*)(ws + OFF_WDN);
  u16* h1     = (u16*)(ws + OFF_H1);
  u16* qkv    = (u16*)(ws + OFF_QKV);
  u16* vT     = (u16*)(ws + OFF_VT);
  u16* av     = (u16*)(ws + OFF_AV);
  float* x1   = (float*)(ws + OFF_X1);
  u8*  h2f8   = (u8*)(ws + OFF_H2F8);
  u16* hid    = (u16*)(ws + OFF_HID);
  float* out  = (float*)d_out;

  prep_weights<<<16384, dim3(32, 8), 0, stream>>>(w_q, w_k, w_v, w_o, w_gate, w_up, w_down,
                                                  wqkv_t, wo_t, wguf8, wdn_t);

  rmsnorm_kernel<0><<<BS_, 256, 0, stream>>>(x, g1, h1);
  // qkv GEMM; V-column blocks write vT directly (EPI 3)
  gemm_bt<128, 3><<<dim3(3072 / 128, BS_ / 128), 256, 0, stream>>>(
      h1, wqkv_t, qkv, nullptr, vT, BS_, 3072, 1024);
  attn_kernel<<<dim3(32, 16), 256, 0, stream>>>(qkv, vT, av);
  gemm_bt<64, 1><<<dim3(1024 / 64, BS_ / 128), 256, 0, stream>>>(
      av, wo_t, x1, x, nullptr, BS_, 1024, 1024);
  rmsnorm_kernel<1><<<BS_, 256, 0, stream>>>(x1, g2, h2f8);
  // fused gate/up GEMM in MX-fp8 (2x MFMA rate)
  gemm_f8<<<dim3(4096 / 64, BS_ / 128), 256, 0, stream>>>(h2f8, wguf8, hid, BS_, 1024);
  gemm_bt<64, 1><<<dim3(1024 / 64, BS_ / 128), 256, 0, stream>>>(
      hid, wdn_t, out, x1, nullptr, BS_, 1024, 4096);
}